// Round 16
// baseline (252.749 us; speedup 1.0000x reference)
//
#include <hip/hip_runtime.h>

// CRF forward: B=512 chains, T=1024, L=48.
// One launch of 1024 blocks x 64 thr (R7 structure, 183us validated):
//   blocks 0..511   : serial alpha-scan, one wave per chain (y_pred only)
//   blocks 512..1023: point+trans scores, parallel over t (validated R6-R13)
// Combined into out[b] via two atomicAdds after hipMemsetAsync(out, 0).
//
// R15 change: the 48x(readlane->fmac) matvec is one inline-asm block,
// software-pipelined 4 deep through s20-s23 -- each v_fmac reads an SGPR
// written 7 instructions earlier (no VALU-SGPR hazard stalls). Accumulator
// mapping (k%8) and sum tree identical to R7 => bitwise-identical results.
// Normalizer: damped lag-2 (c=0.5*log2(e[0]), poles |z|=0.707; validated
// R5-R13, absmax 0.0). Exactness independent of c.

constexpr int Bb = 512;
constexpr int Tt = 1024;
constexpr int Ll = 48;
constexpr int PF = 4;   // scan prefetch depth (steps)

#define LOG2E_F 1.44269504088896340736f
#define LN2_F   0.69314718055994530942f

__device__ __forceinline__ float rl_f(float v, int l) {
    return __uint_as_float(__builtin_amdgcn_readlane(__float_as_uint(v), (unsigned)l));
}
__device__ __forceinline__ float fexp2(float x) { return __builtin_amdgcn_exp2f(x); }
__device__ __forceinline__ float flog2(float x) { return __builtin_amdgcn_logf(x); }

// asm building blocks: RL_(sgpr, lane)  FM_(acc, sgpr, Eidx)
#define RL_(s, k) "v_readlane_b32 s" #s ", %[ve], " #k "\n\t"
#define FM_(a, s, k) "v_fmac_f32 %[a" #a "], s" #s ", %[E" #k "]\n\t"

__global__ __launch_bounds__(64)
__attribute__((amdgpu_waves_per_eu(1, 1)))
void crf_fwd_kernel(const float* __restrict__ y_true,
                    const float* __restrict__ y_pred,
                    const float* __restrict__ trans,
                    float* __restrict__ out)
{
    const int lane = threadIdx.x;
    __shared__ float str[Ll * Ll];

    if (blockIdx.x >= Bb) {
        // -------- score block: chain b, parallel over t (lane j = t0+j) ----
        const int b = blockIdx.x - Bb;
        for (int i = lane; i < Ll * Ll; i += 64) str[i] = trans[i];
        __syncthreads();

        const float* __restrict__ yprow = y_pred + (size_t)b * Tt * Ll;
        const float* __restrict__ ytrow = y_true + (size_t)b * Tt * Ll;

        float ps = 0.f, ts = 0.f;
        int labLast = 0;

        for (int t0 = 0; t0 < Tt; t0 += 64) {
            const int t = t0 + lane;
            const float4* row = (const float4*)(ytrow + (size_t)t * Ll);
            int lab = 0;
            #pragma unroll
            for (int k = 0; k < 12; ++k) {
                float4 v = row[k];
                if (v.x > 0.5f) lab = 4 * k + 0;
                if (v.y > 0.5f) lab = 4 * k + 1;
                if (v.z > 0.5f) lab = 4 * k + 2;
                if (v.w > 0.5f) lab = 4 * k + 3;
            }
            ps += yprow[(size_t)t * Ll + lab];            // point term
            int labPrev = __shfl_up(lab, 1);
            if (lane == 0) labPrev = labLast;             // chunk boundary
            if (t > 0) ts += str[labPrev * Ll + lab];     // trans term
            labLast = __builtin_amdgcn_readlane(lab, 63);
        }

        float acc = ps + ts;
        #pragma unroll
        for (int off = 32; off >= 1; off >>= 1) acc += __shfl_xor(acc, off);
        if (lane == 0) atomicAdd(&out[b], -acc);
        return;
    }

    // ---------------- scan block: chain b = blockIdx.x --------------------
    const int b  = blockIdx.x;
    const int ml = lane < Ll ? lane : (Ll - 1);
    const bool act = lane < Ll;
    for (int i = lane; i < Ll * Ll; i += 64) str[i] = trans[i];
    __syncthreads();

    // Et[l] = exp(trans[l][ml]) as 48 named scalars (static accesses only)
#define MK_E(l) float E##l = fexp2(str[(l) * Ll + ml] * LOG2E_F);
    MK_E(0)  MK_E(1)  MK_E(2)  MK_E(3)  MK_E(4)  MK_E(5)  MK_E(6)  MK_E(7)
    MK_E(8)  MK_E(9)  MK_E(10) MK_E(11) MK_E(12) MK_E(13) MK_E(14) MK_E(15)
    MK_E(16) MK_E(17) MK_E(18) MK_E(19) MK_E(20) MK_E(21) MK_E(22) MK_E(23)
    MK_E(24) MK_E(25) MK_E(26) MK_E(27) MK_E(28) MK_E(29) MK_E(30) MK_E(31)
    MK_E(32) MK_E(33) MK_E(34) MK_E(35) MK_E(36) MK_E(37) MK_E(38) MK_E(39)
    MK_E(40) MK_E(41) MK_E(42) MK_E(43) MK_E(44) MK_E(45) MK_E(46) MK_E(47)
#undef MK_E

    const float* __restrict__ yprow = y_pred + (size_t)b * Tt * Ll;

    float raw0 = yprow[ml];
    float e = fexp2(raw0 * LOG2E_F);              // e_0[m], S = 0
    float S = 0.f;
    float cUse = 0.5f * rl_f(raw0, 0) * LOG2E_F;  // 0.5*log2(e_0[0])

    // 48-term broadcast matvec, pipelined 4-deep through s20..s23.
    // fmac k reads s{20+k%4} written 7 instructions earlier; acc = a{k%8}.
#define MATVEC48()                                                       \
    asm volatile(                                                        \
        "s_nop 1\n\t"                                                    \
        RL_(20,0) RL_(21,1) RL_(22,2) RL_(23,3)                          \
        FM_(0,20,0)   RL_(20,4)                                          \
        FM_(1,21,1)   RL_(21,5)                                          \
        FM_(2,22,2)   RL_(22,6)                                          \
        FM_(3,23,3)   RL_(23,7)                                          \
        FM_(4,20,4)   RL_(20,8)                                          \
        FM_(5,21,5)   RL_(21,9)                                          \
        FM_(6,22,6)   RL_(22,10)                                         \
        FM_(7,23,7)   RL_(23,11)                                         \
        FM_(0,20,8)   RL_(20,12)                                         \
        FM_(1,21,9)   RL_(21,13)                                         \
        FM_(2,22,10)  RL_(22,14)                                         \
        FM_(3,23,11)  RL_(23,15)                                         \
        FM_(4,20,12)  RL_(20,16)                                         \
        FM_(5,21,13)  RL_(21,17)                                         \
        FM_(6,22,14)  RL_(22,18)                                         \
        FM_(7,23,15)  RL_(23,19)                                         \
        FM_(0,20,16)  RL_(20,20)                                         \
        FM_(1,21,17)  RL_(21,21)                                         \
        FM_(2,22,18)  RL_(22,22)                                         \
        FM_(3,23,19)  RL_(23,23)                                         \
        FM_(4,20,20)  RL_(20,24)                                         \
        FM_(5,21,21)  RL_(21,25)                                         \
        FM_(6,22,22)  RL_(22,26)                                         \
        FM_(7,23,23)  RL_(23,27)                                         \
        FM_(0,20,24)  RL_(20,28)                                         \
        FM_(1,21,25)  RL_(21,29)                                         \
        FM_(2,22,26)  RL_(22,30)                                         \
        FM_(3,23,27)  RL_(23,31)                                         \
        FM_(4,20,28)  RL_(20,32)                                         \
        FM_(5,21,29)  RL_(21,33)                                         \
        FM_(6,22,30)  RL_(22,34)                                         \
        FM_(7,23,31)  RL_(23,35)                                         \
        FM_(0,20,32)  RL_(20,36)                                         \
        FM_(1,21,33)  RL_(21,37)                                         \
        FM_(2,22,34)  RL_(22,38)                                         \
        FM_(3,23,35)  RL_(23,39)                                         \
        FM_(4,20,36)  RL_(20,40)                                         \
        FM_(5,21,37)  RL_(21,41)                                         \
        FM_(6,22,38)  RL_(22,42)                                         \
        FM_(7,23,39)  RL_(23,43)                                         \
        FM_(0,20,40)  RL_(20,44)                                         \
        FM_(1,21,41)  RL_(21,45)                                         \
        FM_(2,22,42)  RL_(22,46)                                         \
        FM_(3,23,43)  RL_(23,47)                                         \
        FM_(4,20,44)                                                     \
        FM_(5,21,45)                                                     \
        FM_(6,22,46)                                                     \
        FM_(7,23,47)                                                     \
        : [a0]"+v"(a0), [a1]"+v"(a1), [a2]"+v"(a2), [a3]"+v"(a3),        \
          [a4]"+v"(a4), [a5]"+v"(a5), [a6]"+v"(a6), [a7]"+v"(a7)         \
        : [ve]"v"(e),                                                    \
          [E0]"v"(E0),   [E1]"v"(E1),   [E2]"v"(E2),   [E3]"v"(E3),      \
          [E4]"v"(E4),   [E5]"v"(E5),   [E6]"v"(E6),   [E7]"v"(E7),      \
          [E8]"v"(E8),   [E9]"v"(E9),   [E10]"v"(E10), [E11]"v"(E11),    \
          [E12]"v"(E12), [E13]"v"(E13), [E14]"v"(E14), [E15]"v"(E15),    \
          [E16]"v"(E16), [E17]"v"(E17), [E18]"v"(E18), [E19]"v"(E19),    \
          [E20]"v"(E20), [E21]"v"(E21), [E22]"v"(E22), [E23]"v"(E23),    \
          [E24]"v"(E24), [E25]"v"(E25), [E26]"v"(E26), [E27]"v"(E27),    \
          [E28]"v"(E28), [E29]"v"(E29), [E30]"v"(E30), [E31]"v"(E31),    \
          [E32]"v"(E32), [E33]"v"(E33), [E34]"v"(E34), [E35]"v"(E35),    \
          [E36]"v"(E36), [E37]"v"(E37), [E38]"v"(E38), [E39]"v"(E39),    \
          [E40]"v"(E40), [E41]"v"(E41), [E42]"v"(E42), [E43]"v"(E43),    \
          [E44]"v"(E44), [E45]"v"(E45), [E46]"v"(E46), [E47]"v"(E47)     \
        : "s20", "s21", "s22", "s23")

#define STEP(raw)                                                        \
    do {                                                                 \
        float cNew = 0.5f * flog2(rl_f(e, 0));                           \
        cNew = fminf(50.f, fmaxf(-50.f, cNew));                          \
        float w = fexp2(fmaf((raw), LOG2E_F, -cUse));                    \
        S += cUse;                                                       \
        cUse = cNew;                                                     \
        float a0 = 0.f, a1 = 0.f, a2 = 0.f, a3 = 0.f;                    \
        float a4 = 0.f, a5 = 0.f, a6 = 0.f, a7 = 0.f;                    \
        MATVEC48();                                                      \
        e = (((a0 + a1) + (a2 + a3)) + ((a4 + a5) + (a6 + a7))) * w;     \
    } while (0)

    float pfP[PF];
    #pragma unroll
    for (int j = 0; j < PF; ++j) pfP[j] = yprow[(1 + j) * Ll + ml];

    for (int t0 = 1; t0 <= Tt - PF - 3; t0 += PF) {
        #pragma unroll
        for (int j = 0; j < PF; ++j) {
            float raw = pfP[j];
            int tn = t0 + j + PF;
            tn = tn < Tt ? tn : (Tt - 1);       // clamp (harmless reload)
            pfP[j] = yprow[tn * Ll + ml];
            STEP(raw);
        }
    }
    STEP(pfP[0]);
    STEP(pfP[1]);
    STEP(pfP[2]);
#undef STEP
#undef MATVEC48

    float es = act ? e : 0.f;
    #pragma unroll
    for (int off = 32; off >= 1; off >>= 1) es += __shfl_xor(es, off);

    if (lane == 0)
        atomicAdd(&out[b], LN2_F * (S + flog2(es)));
}

extern "C" void kernel_launch(void* const* d_in, const int* in_sizes, int n_in,
                              void* d_out, int out_size, void* d_ws, size_t ws_size,
                              hipStream_t stream) {
    const float* y_true = (const float*)d_in[0];
    const float* y_pred = (const float*)d_in[1];
    const float* trans  = (const float*)d_in[2];
    float* out = (float*)d_out;

    hipMemsetAsync(d_out, 0, (size_t)out_size * sizeof(float), stream);
    crf_fwd_kernel<<<2 * Bb, 64, 0, stream>>>(y_true, y_pred, trans, out);
}